// Round 2
// baseline (5012.632 us; speedup 1.0000x reference)
//
#include <hip/hip_runtime.h>
#include <hip/hip_bf16.h>

#define U_N 100000
#define V_N 50000
#define A_N 5000

typedef float4 f4;

// cur = acc = concat(a[na,64], b[nb,64])
__global__ void k_concat2(const float* __restrict__ a, int na,
                          const float* __restrict__ b, int nb,
                          float* __restrict__ cur, float* __restrict__ acc) {
  int total4 = (na + nb) * 16;
  for (int i = blockIdx.x * blockDim.x + threadIdx.x; i < total4;
       i += gridDim.x * blockDim.x) {
    int fi = i * 4;
    f4 v = (fi < na * 64) ? *(const f4*)(a + fi)
                          : *(const f4*)(b + (fi - na * 64));
    *(f4*)(cur + fi) = v;
    *(f4*)(acc + fi) = v;
  }
}

// out[r*stride + coloff + d] += val * in[(in_off+c)*64 + d]; wave per nnz
__global__ void k_spmm(const int* __restrict__ rows, const int* __restrict__ cols,
                       const float* __restrict__ vals, int nnz,
                       const float* __restrict__ in, int in_off,
                       float* __restrict__ out, int out_stride, int out_coloff) {
  int lane = threadIdx.x & 63;
  int wid = (blockIdx.x * blockDim.x + threadIdx.x) >> 6;
  int nw = (gridDim.x * blockDim.x) >> 6;
  for (int e = wid; e < nnz; e += nw) {
    int r = rows[e];
    int c = cols[e];
    float v = vals[e];
    float x = in[(in_off + c) * 64 + lane];
    atomicAdd(out + r * out_stride + out_coloff + lane, v * x);
  }
}

__global__ void k_add(float* __restrict__ acc, const float* __restrict__ src, int n4) {
  for (int i = blockIdx.x * blockDim.x + threadIdx.x; i < n4;
       i += gridDim.x * blockDim.x) {
    f4 a = *(f4*)(acc + i * 4);
    f4 s = *(const f4*)(src + i * 4);
    a.x += s.x; a.y += s.y; a.z += s.z; a.w += s.w;
    *(f4*)(acc + i * 4) = a;
  }
}

__global__ void k_scale(float* __restrict__ p, int n4) {
  for (int i = blockIdx.x * blockDim.x + threadIdx.x; i < n4;
       i += gridDim.x * blockDim.x) {
    f4 v = *(f4*)(p + i * 4);
    v.x *= 0.25f; v.y *= 0.25f; v.z *= 0.25f; v.w *= 0.25f;
    *(f4*)(p + i * 4) = v;
  }
}

// accUI *= 0.25 in place; video rows also copied to VA[:, :64] (stride 128)
__global__ void k_scale_ui(float* __restrict__ acc, float* __restrict__ VA) {
  int total4 = 150000 * 16;
  for (int i = blockIdx.x * blockDim.x + threadIdx.x; i < total4;
       i += gridDim.x * blockDim.x) {
    int fi = i * 4;
    f4 v = *(f4*)(acc + fi);
    v.x *= 0.25f; v.y *= 0.25f; v.z *= 0.25f; v.w *= 0.25f;
    *(f4*)(acc + fi) = v;
    if (fi >= U_N * 64) {
      int rem = fi - U_N * 64;
      int row = rem >> 6, col = rem & 63;
      *(f4*)(VA + row * 128 + col) = v;
    }
  }
}

// rowwise x / max(||x||, 1e-12), wave per row
__global__ void k_l2norm(float* __restrict__ p, int nrows, int stride, int coloff) {
  int lane = threadIdx.x & 63;
  int w = (blockIdx.x * blockDim.x + threadIdx.x) >> 6;
  int nw = (gridDim.x * blockDim.x) >> 6;
  for (int r = w; r < nrows; r += nw) {
    float* row = p + r * stride + coloff;
    float x = row[lane];
    float s = x * x;
    #pragma unroll
    for (int off = 32; off; off >>= 1) s += __shfl_xor(s, off, 64);
    float inv = 1.0f / fmaxf(sqrtf(s), 1e-12f);
    row[lane] = x * inv;
  }
}

// Ucat[b] = [atom_u[users[b]] | non_u[users[b]]]
__global__ void k_gather_u(const int* __restrict__ users,
                           const float* __restrict__ accUI,
                           const float* __restrict__ accUA,
                           float* __restrict__ Ucat) {
  int b = blockIdx.x;
  int d = threadIdx.x;
  int u = users[b];
  Ucat[b * 128 + d] = accUI[u * 64 + d];
  Ucat[b * 128 + 64 + d] = accUA[u * 64 + d];
}

// VB[v] = [atom_a[vl[v]] | non_a[vl[v]]]
__global__ void k_gather_vb(const int* __restrict__ vlist,
                            const float* __restrict__ atomA,
                            const float* __restrict__ accUA,
                            float* __restrict__ VB) {
  int v = blockIdx.x * 4 + (threadIdx.x >> 6);
  int d = threadIdx.x & 63;
  int a = vlist[v];
  VB[v * 128 + d] = atomA[a * 64 + d];
  VB[v * 128 + 64 + d] = accUA[(U_N + a) * 64 + d];
}

// w[v] = sigmoid( dot( ((atom_v+non_v)/2) @ q , (vl_a+vl_n)/2 ) )
__global__ void k_w(const float* __restrict__ VA, const float* __restrict__ VB,
                    const float* __restrict__ q, float* __restrict__ wv) {
  __shared__ float qs[64 * 64];
  for (int i = threadIdx.x; i < 4096; i += blockDim.x) qs[i] = q[i];
  __syncthreads();
  int lane = threadIdx.x & 63;
  int v = blockIdx.x * 4 + (threadIdx.x >> 6);
  if (v >= V_N) return;
  float vid = 0.5f * (VA[v * 128 + lane] + VA[v * 128 + 64 + lane]);
  float vlog = 0.5f * (VB[v * 128 + lane] + VB[v * 128 + 64 + lane]);
  float s = 0.0f;
  for (int d = 0; d < 64; ++d)
    s = fmaf(__shfl(vid, d, 64), qs[d * 64 + lane], s);
  float t = s * vlog;
  #pragma unroll
  for (int off = 32; off; off >>= 1) t += __shfl_xor(t, off, 64);
  if (lane == 0) wv[v] = 1.0f / (1.0f + __expf(-t));
}

// out[b,v] = w[v]*sig(Ucat[b]·VA[v]) + (1-w[v])*sig(Ucat[b]·VB[v])
// 32u x 32v tile, 256 threads, 2x2 register block. LDS = 3*32*132*4 = 50688 B.
#define TSTRIDE 132
__global__ __launch_bounds__(256) void k_rating(
    const float* __restrict__ Ucat, const float* __restrict__ VA,
    const float* __restrict__ VB, const float* __restrict__ wv,
    float* __restrict__ out) {
  __shared__ float Us[32 * TSTRIDE];
  __shared__ float Va[32 * TSTRIDE];
  __shared__ float Vb[32 * TSTRIDE];
  int bv = blockIdx.x, bu = blockIdx.y;
  int u0 = bu * 32, v0 = bv * 32;
  int t = threadIdx.x;
  // load tiles: 32 rows x 128 floats = 1024 f4 per tile, 4 per thread
  for (int i = t; i < 1024; i += 256) {
    int row = i >> 5, c4 = (i & 31) * 4;
    *(f4*)(Us + row * TSTRIDE + c4) = *(const f4*)(Ucat + (u0 + row) * 128 + c4);
    int v = v0 + row;
    f4 a = make_float4(0, 0, 0, 0), b = make_float4(0, 0, 0, 0);
    if (v < V_N) {
      a = *(const f4*)(VA + (size_t)v * 128 + c4);
      b = *(const f4*)(VB + (size_t)v * 128 + c4);
    }
    *(f4*)(Va + row * TSTRIDE + c4) = a;
    *(f4*)(Vb + row * TSTRIDE + c4) = b;
  }
  __syncthreads();
  int tx = t & 15;   // video: v = v0 + tx + j*16
  int ty = t >> 4;   // user:  u = u0 + ty + i*16
  float accA[2][2] = {{0.f}}, accB[2][2] = {{0.f}};
  for (int k = 0; k < 128; k += 4) {
    f4 a0 = *(const f4*)(Us + ty * TSTRIDE + k);
    f4 a1 = *(const f4*)(Us + (ty + 16) * TSTRIDE + k);
    f4 va0 = *(const f4*)(Va + tx * TSTRIDE + k);
    f4 va1 = *(const f4*)(Va + (tx + 16) * TSTRIDE + k);
    f4 vb0 = *(const f4*)(Vb + tx * TSTRIDE + k);
    f4 vb1 = *(const f4*)(Vb + (tx + 16) * TSTRIDE + k);
    accA[0][0] = fmaf(a0.x, va0.x, fmaf(a0.y, va0.y, fmaf(a0.z, va0.z, fmaf(a0.w, va0.w, accA[0][0]))));
    accA[0][1] = fmaf(a0.x, va1.x, fmaf(a0.y, va1.y, fmaf(a0.z, va1.z, fmaf(a0.w, va1.w, accA[0][1]))));
    accA[1][0] = fmaf(a1.x, va0.x, fmaf(a1.y, va0.y, fmaf(a1.z, va0.z, fmaf(a1.w, va0.w, accA[1][0]))));
    accA[1][1] = fmaf(a1.x, va1.x, fmaf(a1.y, va1.y, fmaf(a1.z, va1.z, fmaf(a1.w, va1.w, accA[1][1]))));
    accB[0][0] = fmaf(a0.x, vb0.x, fmaf(a0.y, vb0.y, fmaf(a0.z, vb0.z, fmaf(a0.w, vb0.w, accB[0][0]))));
    accB[0][1] = fmaf(a0.x, vb1.x, fmaf(a0.y, vb1.y, fmaf(a0.z, vb1.z, fmaf(a0.w, vb1.w, accB[0][1]))));
    accB[1][0] = fmaf(a1.x, vb0.x, fmaf(a1.y, vb0.y, fmaf(a1.z, vb0.z, fmaf(a1.w, vb0.w, accB[1][0]))));
    accB[1][1] = fmaf(a1.x, vb1.x, fmaf(a1.y, vb1.y, fmaf(a1.z, vb1.z, fmaf(a1.w, vb1.w, accB[1][1]))));
  }
  #pragma unroll
  for (int i = 0; i < 2; ++i) {
    int u = u0 + ty + i * 16;
    #pragma unroll
    for (int j = 0; j < 2; ++j) {
      int v = v0 + tx + j * 16;
      if (v < V_N) {
        float wvv = wv[v];
        float sa = 1.0f / (1.0f + __expf(-accA[i][j]));
        float sb = 1.0f / (1.0f + __expf(-accB[i][j]));
        out[(size_t)u * V_N + v] = wvv * sa + (1.0f - wvv) * sb;
      }
    }
  }
}

extern "C" void kernel_launch(void* const* d_in, const int* in_sizes, int n_in,
                              void* d_out, int out_size, void* d_ws, size_t ws_size,
                              hipStream_t stream) {
  const float* emb_user    = (const float*)d_in[0];
  const float* emb_video   = (const float*)d_in[1];
  const float* emb_vlogger = (const float*)d_in[2];
  const float* q           = (const float*)d_in[3];
  const int*   ui_rows = (const int*)d_in[4];
  const int*   ui_cols = (const int*)d_in[5];
  const float* ui_vals = (const float*)d_in[6];
  const int*   ua_rows = (const int*)d_in[7];
  const int*   ua_cols = (const int*)d_in[8];
  const float* ua_vals = (const float*)d_in[9];
  const int*   g2_rows = (const int*)d_in[10];
  const int*   g2_cols = (const int*)d_in[11];
  const float* g2_vals = (const float*)d_in[12];
  const int*   g4_rows = (const int*)d_in[13];
  const int*   g4_cols = (const int*)d_in[14];
  const float* g4_vals = (const float*)d_in[15];
  const int*   vlist   = (const int*)d_in[16];
  const int*   users   = (const int*)d_in[17];
  int nnz_ui = in_sizes[4], nnz_ua = in_sizes[7];
  int nnz_g2 = in_sizes[10], nnz_g4 = in_sizes[13];

  float* ws = (float*)d_ws;
  float* cur   = ws;                  // 9,600,000 floats
  float* nxt   = ws + 9600000;        // 9,600,000
  float* accUI = ws + 19200000;       // 9,600,000 (atom_u|atom_v)
  float* accUA = ws + 28800000;       // 6,720,000 (non_u|non_a)
  // aliases (cur/nxt are dead after the two propagations):
  float* atomA = cur;                 //   320,000
  float* VB    = cur + 320000;        // 6,400,000 [vl_a|vl_n]
  float* Ucat  = cur + 6720000;       //   131,072 [u_a|u_n]
  float* wv    = cur + 6851072;       //    50,000
  float* VA    = nxt;                 // 6,400,000 [atom_v|non_v]

  const int nUI = U_N + V_N, nUA = U_N + A_N;

  // ---- UI propagation ----
  k_concat2<<<2048, 256, 0, stream>>>(emb_user, U_N, emb_video, V_N, cur, accUI);
  {
    float* p0 = cur; float* p1 = nxt;
    for (int l = 0; l < 3; ++l) {
      hipMemsetAsync(p1, 0, (size_t)nUI * 64 * 4, stream);
      k_spmm<<<8192, 256, 0, stream>>>(ui_rows, ui_cols, ui_vals, nnz_ui, p0, 0, p1, 64, 0);
      k_add<<<2048, 256, 0, stream>>>(accUI, p1, nUI * 16);
      float* tmp = p0; p0 = p1; p1 = tmp;
    }
  }
  // ---- UA propagation (reuses cur/nxt) ----
  k_concat2<<<2048, 256, 0, stream>>>(emb_user, U_N, emb_vlogger, A_N, cur, accUA);
  {
    float* p0 = cur; float* p1 = nxt;
    for (int l = 0; l < 3; ++l) {
      hipMemsetAsync(p1, 0, (size_t)nUA * 64 * 4, stream);
      k_spmm<<<8192, 256, 0, stream>>>(ua_rows, ua_cols, ua_vals, nnz_ua, p0, 0, p1, 64, 0);
      k_add<<<2048, 256, 0, stream>>>(accUA, p1, nUA * 16);
      float* tmp = p0; p0 = p1; p1 = tmp;
    }
  }
  // ---- scales (l2norm branches are scale-invariant, dots need /4) ----
  k_scale<<<2048, 256, 0, stream>>>(accUA, nUA * 16);
  hipMemsetAsync(VA, 0, (size_t)V_N * 128 * 4, stream);
  k_scale_ui<<<2048, 256, 0, stream>>>(accUI, VA);
  // ---- atom_a = l2norm(spmm(g2, atom_v)) ----
  hipMemsetAsync(atomA, 0, (size_t)A_N * 64 * 4, stream);
  k_spmm<<<2048, 256, 0, stream>>>(g2_rows, g2_cols, g2_vals, nnz_g2, accUI, U_N, atomA, 64, 0);
  k_l2norm<<<1280, 256, 0, stream>>>(atomA, A_N, 64, 0);
  // ---- non_v = l2norm(spmm(g4, non_u)) into VA[:,64:] ----
  k_spmm<<<8192, 256, 0, stream>>>(g4_rows, g4_cols, g4_vals, nnz_g4, accUA, 0, VA, 128, 64);
  k_l2norm<<<12500, 256, 0, stream>>>(VA, V_N, 128, 64);
  // ---- gathers ----
  k_gather_u<<<1024, 64, 0, stream>>>(users, accUI, accUA, Ucat);
  k_gather_vb<<<12500, 256, 0, stream>>>(vlist, atomA, accUA, VB);
  // ---- w ----
  k_w<<<12500, 256, 0, stream>>>(VA, VB, q, wv);
  // ---- rating: 32x32 tiles ----
  dim3 gridR((V_N + 31) / 32, 1024 / 32);
  k_rating<<<gridR, 256, 0, stream>>>(Ucat, VA, VB, wv, (float*)d_out);
}

// Round 3
// 3202.125 us; speedup vs baseline: 1.5654x; 1.5654x over previous
//
#include <hip/hip_runtime.h>
#include <hip/hip_bf16.h>

#define U_N 100000
#define V_N 50000
#define A_N 5000

typedef float4 f4;

// cur = acc = concat(a[na,64], b[nb,64])
__global__ void k_concat2(const float* __restrict__ a, int na,
                          const float* __restrict__ b, int nb,
                          float* __restrict__ cur, float* __restrict__ acc) {
  int total4 = (na + nb) * 16;
  for (int i = blockIdx.x * blockDim.x + threadIdx.x; i < total4;
       i += gridDim.x * blockDim.x) {
    int fi = i * 4;
    f4 v = (fi < na * 64) ? *(const f4*)(a + fi)
                          : *(const f4*)(b + (fi - na * 64));
    *(f4*)(cur + fi) = v;
    *(f4*)(acc + fi) = v;
  }
}

// ---------------- CSR build ----------------
__global__ void k_count(const int* __restrict__ rows, int nnz, int* __restrict__ cnt) {
  for (int i = blockIdx.x * blockDim.x + threadIdx.x; i < nnz;
       i += gridDim.x * blockDim.x)
    atomicAdd(&cnt[rows[i]], 1);
}

// cnt_pos: in = counts, out = start positions (same array). rp[0..n] exclusive scan.
__global__ void k_scan(int* __restrict__ cnt_pos, int n, int* __restrict__ rp) {
  __shared__ int part[1024];
  int t = threadIdx.x;
  int chunk = (n + 1023) >> 10;
  int b = t * chunk;
  int e = min(b + chunk, n);
  int s = 0;
  for (int i = b; i < e; ++i) s += cnt_pos[i];
  part[t] = s;
  __syncthreads();
  for (int off = 1; off < 1024; off <<= 1) {
    int v = (t >= off) ? part[t - off] : 0;
    __syncthreads();
    part[t] += v;
    __syncthreads();
  }
  int run = (t == 0) ? 0 : part[t - 1];
  for (int i = b; i < e; ++i) {
    int c = cnt_pos[i];
    rp[i] = run;
    cnt_pos[i] = run;
    run += c;
  }
  if (t == 1023) rp[n] = part[1023];
}

__global__ void k_fill(const int* __restrict__ rows, const int* __restrict__ cols,
                       const float* __restrict__ vals, int nnz,
                       int* __restrict__ pos, int* __restrict__ ci,
                       float* __restrict__ cv) {
  for (int i = blockIdx.x * blockDim.x + threadIdx.x; i < nnz;
       i += gridDim.x * blockDim.x) {
    int slot = atomicAdd(&pos[rows[i]], 1);
    ci[slot] = cols[i];
    cv[slot] = vals[i];
  }
}

// ---------------- gather SpMM: wave per row, lane = dim ----------------
__global__ void k_spmm_csr(const int* __restrict__ rp, const int* __restrict__ ci,
                           const float* __restrict__ cv, int nrows,
                           const float* __restrict__ in, int in_off,
                           float* __restrict__ outc, int ostride, int ocoloff,
                           float* __restrict__ acc) {
  int lane = threadIdx.x & 63;
  int w = (blockIdx.x * blockDim.x + threadIdx.x) >> 6;
  int nw = (gridDim.x * blockDim.x) >> 6;
  for (int r = w; r < nrows; r += nw) {
    int e0 = rp[r], e1 = rp[r + 1];
    float s0 = 0.f, s1 = 0.f;
    int e = e0;
    for (; e + 1 < e1; e += 2) {
      int c0 = ci[e], c1 = ci[e + 1];
      float v0 = cv[e], v1 = cv[e + 1];
      s0 = fmaf(v0, in[(size_t)(in_off + c0) * 64 + lane], s0);
      s1 = fmaf(v1, in[(size_t)(in_off + c1) * 64 + lane], s1);
    }
    if (e < e1) s0 = fmaf(cv[e], in[(size_t)(in_off + ci[e]) * 64 + lane], s0);
    float s = s0 + s1;
    outc[(size_t)r * ostride + ocoloff + lane] = s;
    if (acc) acc[(size_t)r * 64 + lane] += s;
  }
}

// ---------------- atomic SpMM fallback (small ws) ----------------
__global__ void k_spmm(const int* __restrict__ rows, const int* __restrict__ cols,
                       const float* __restrict__ vals, int nnz,
                       const float* __restrict__ in, int in_off,
                       float* __restrict__ out, int out_stride, int out_coloff) {
  int lane = threadIdx.x & 63;
  int wid = (blockIdx.x * blockDim.x + threadIdx.x) >> 6;
  int nw = (gridDim.x * blockDim.x) >> 6;
  for (int e = wid; e < nnz; e += nw) {
    int r = rows[e];
    int c = cols[e];
    float v = vals[e];
    float x = in[(size_t)(in_off + c) * 64 + lane];
    atomicAdd(out + (size_t)r * out_stride + out_coloff + lane, v * x);
  }
}

__global__ void k_add(float* __restrict__ acc, const float* __restrict__ src, int n4) {
  for (int i = blockIdx.x * blockDim.x + threadIdx.x; i < n4;
       i += gridDim.x * blockDim.x) {
    f4 a = *(f4*)(acc + i * 4);
    f4 s = *(const f4*)(src + i * 4);
    a.x += s.x; a.y += s.y; a.z += s.z; a.w += s.w;
    *(f4*)(acc + i * 4) = a;
  }
}

__global__ void k_scale(float* __restrict__ p, int n4) {
  for (int i = blockIdx.x * blockDim.x + threadIdx.x; i < n4;
       i += gridDim.x * blockDim.x) {
    f4 v = *(f4*)(p + i * 4);
    v.x *= 0.25f; v.y *= 0.25f; v.z *= 0.25f; v.w *= 0.25f;
    *(f4*)(p + i * 4) = v;
  }
}

// accUI *= 0.25 in place; video rows also copied to VA[:, :64] (stride 128)
__global__ void k_scale_ui(float* __restrict__ acc, float* __restrict__ VA) {
  int total4 = 150000 * 16;
  for (int i = blockIdx.x * blockDim.x + threadIdx.x; i < total4;
       i += gridDim.x * blockDim.x) {
    int fi = i * 4;
    f4 v = *(f4*)(acc + fi);
    v.x *= 0.25f; v.y *= 0.25f; v.z *= 0.25f; v.w *= 0.25f;
    *(f4*)(acc + fi) = v;
    if (fi >= U_N * 64) {
      int rem = fi - U_N * 64;
      int row = rem >> 6, col = rem & 63;
      *(f4*)(VA + row * 128 + col) = v;
    }
  }
}

// rowwise x / max(||x||, 1e-12), wave per row
__global__ void k_l2norm(float* __restrict__ p, int nrows, int stride, int coloff) {
  int lane = threadIdx.x & 63;
  int w = (blockIdx.x * blockDim.x + threadIdx.x) >> 6;
  int nw = (gridDim.x * blockDim.x) >> 6;
  for (int r = w; r < nrows; r += nw) {
    float* row = p + (size_t)r * stride + coloff;
    float x = row[lane];
    float s = x * x;
    #pragma unroll
    for (int off = 32; off; off >>= 1) s += __shfl_xor(s, off, 64);
    float inv = 1.0f / fmaxf(sqrtf(s), 1e-12f);
    row[lane] = x * inv;
  }
}

__global__ void k_gather_u(const int* __restrict__ users,
                           const float* __restrict__ accUI,
                           const float* __restrict__ accUA,
                           float* __restrict__ Ucat) {
  int b = blockIdx.x;
  int d = threadIdx.x;
  int u = users[b];
  Ucat[b * 128 + d] = accUI[(size_t)u * 64 + d];
  Ucat[b * 128 + 64 + d] = accUA[(size_t)u * 64 + d];
}

__global__ void k_gather_vb(const int* __restrict__ vlist,
                            const float* __restrict__ atomA,
                            const float* __restrict__ accUA,
                            float* __restrict__ VB) {
  int v = blockIdx.x * 4 + (threadIdx.x >> 6);
  int d = threadIdx.x & 63;
  int a = vlist[v];
  VB[(size_t)v * 128 + d] = atomA[(size_t)a * 64 + d];
  VB[(size_t)v * 128 + 64 + d] = accUA[(size_t)(U_N + a) * 64 + d];
}

// w[v] = sigmoid( dot( ((atom_v+non_v)/2) @ q , (vl_a+vl_n)/2 ) )
__global__ void k_w(const float* __restrict__ VA, const float* __restrict__ VB,
                    const float* __restrict__ q, float* __restrict__ wv) {
  __shared__ float qs[64 * 64];
  for (int i = threadIdx.x; i < 4096; i += blockDim.x) qs[i] = q[i];
  __syncthreads();
  int lane = threadIdx.x & 63;
  int v = blockIdx.x * 4 + (threadIdx.x >> 6);
  if (v >= V_N) return;
  float vid = 0.5f * (VA[(size_t)v * 128 + lane] + VA[(size_t)v * 128 + 64 + lane]);
  float vlog = 0.5f * (VB[(size_t)v * 128 + lane] + VB[(size_t)v * 128 + 64 + lane]);
  float s = 0.0f;
  for (int d = 0; d < 64; ++d)
    s = fmaf(__shfl(vid, d, 64), qs[d * 64 + lane], s);
  float t = s * vlog;
  #pragma unroll
  for (int off = 32; off; off >>= 1) t += __shfl_xor(t, off, 64);
  if (lane == 0) wv[v] = 1.0f / (1.0f + __expf(-t));
}

// out[b,v] = w[v]*sig(Ucat[b]·VA[v]) + (1-w[v])*sig(Ucat[b]·VB[v])
// 64u x 64v tile, 256 threads, 4x4 register block, K chunked in 2 x 64.
// LDS = 3 * 64 * 68 * 4 = 52224 B.
#define TS 68
__global__ __launch_bounds__(256) void k_rating(
    const float* __restrict__ Ucat, const float* __restrict__ VA,
    const float* __restrict__ VB, const float* __restrict__ wv,
    float* __restrict__ out) {
  __shared__ float Us[64 * TS];
  __shared__ float Va[64 * TS];
  __shared__ float Vb[64 * TS];
  int v0 = blockIdx.x * 64, u0 = blockIdx.y * 64;
  int t = threadIdx.x, tx = t & 15, ty = t >> 4;
  float accA[4][4] = {{0.f}}, accB[4][4] = {{0.f}};
  for (int kc = 0; kc < 128; kc += 64) {
    __syncthreads();
    for (int i = t; i < 1024; i += 256) {
      int row = i >> 4, c4 = (i & 15) << 2;
      *(f4*)(Us + row * TS + c4) =
          *(const f4*)(Ucat + (size_t)(u0 + row) * 128 + kc + c4);
      int v = v0 + row;
      f4 a = make_float4(0, 0, 0, 0), b = make_float4(0, 0, 0, 0);
      if (v < V_N) {
        a = *(const f4*)(VA + (size_t)v * 128 + kc + c4);
        b = *(const f4*)(VB + (size_t)v * 128 + kc + c4);
      }
      *(f4*)(Va + row * TS + c4) = a;
      *(f4*)(Vb + row * TS + c4) = b;
    }
    __syncthreads();
    for (int k = 0; k < 64; k += 4) {
      f4 av[4], va[4], vb[4];
      #pragma unroll
      for (int ii = 0; ii < 4; ++ii)
        av[ii] = *(const f4*)(Us + (ty + ii * 16) * TS + k);
      #pragma unroll
      for (int jj = 0; jj < 4; ++jj) {
        va[jj] = *(const f4*)(Va + (tx + jj * 16) * TS + k);
        vb[jj] = *(const f4*)(Vb + (tx + jj * 16) * TS + k);
      }
      #pragma unroll
      for (int ii = 0; ii < 4; ++ii) {
        #pragma unroll
        for (int jj = 0; jj < 4; ++jj) {
          accA[ii][jj] = fmaf(av[ii].x, va[jj].x, fmaf(av[ii].y, va[jj].y,
                         fmaf(av[ii].z, va[jj].z, fmaf(av[ii].w, va[jj].w, accA[ii][jj]))));
          accB[ii][jj] = fmaf(av[ii].x, vb[jj].x, fmaf(av[ii].y, vb[jj].y,
                         fmaf(av[ii].z, vb[jj].z, fmaf(av[ii].w, vb[jj].w, accB[ii][jj]))));
        }
      }
    }
  }
  #pragma unroll
  for (int jj = 0; jj < 4; ++jj) {
    int v = v0 + tx + jj * 16;
    if (v < V_N) {
      float wvv = wv[v];
      #pragma unroll
      for (int ii = 0; ii < 4; ++ii) {
        int u = u0 + ty + ii * 16;
        float sa = 1.0f / (1.0f + __expf(-accA[ii][jj]));
        float sb = 1.0f / (1.0f + __expf(-accB[ii][jj]));
        out[(size_t)u * V_N + v] = wvv * sa + (1.0f - wvv) * sb;
      }
    }
  }
}

extern "C" void kernel_launch(void* const* d_in, const int* in_sizes, int n_in,
                              void* d_out, int out_size, void* d_ws, size_t ws_size,
                              hipStream_t stream) {
  const float* emb_user    = (const float*)d_in[0];
  const float* emb_video   = (const float*)d_in[1];
  const float* emb_vlogger = (const float*)d_in[2];
  const float* q           = (const float*)d_in[3];
  const int*   ui_rows = (const int*)d_in[4];
  const int*   ui_cols = (const int*)d_in[5];
  const float* ui_vals = (const float*)d_in[6];
  const int*   ua_rows = (const int*)d_in[7];
  const int*   ua_cols = (const int*)d_in[8];
  const float* ua_vals = (const float*)d_in[9];
  const int*   g2_rows = (const int*)d_in[10];
  const int*   g2_cols = (const int*)d_in[11];
  const float* g2_vals = (const float*)d_in[12];
  const int*   g4_rows = (const int*)d_in[13];
  const int*   g4_cols = (const int*)d_in[14];
  const float* g4_vals = (const float*)d_in[15];
  const int*   vlist   = (const int*)d_in[16];
  const int*   users   = (const int*)d_in[17];
  int nnz_ui = in_sizes[4], nnz_ua = in_sizes[7];
  int nnz_g2 = in_sizes[10], nnz_g4 = in_sizes[13];

  float* ws = (float*)d_ws;
  float* cur   = ws;                  // 9,600,000 floats
  float* nxt   = ws + 9600000;        // 9,600,000
  float* accUI = ws + 19200000;       // 9,600,000 (atom_u|atom_v)
  float* accUA = ws + 28800000;       // 6,720,000 (non_u|non_a)
  // post-propagation aliases (cur/nxt dead then):
  float* atomA = cur;                 //   320,000
  float* VB    = cur + 320000;        // 6,400,000 [vl_a|vl_n]
  float* Ucat  = cur + 6720000;       //   131,072 [u_a|u_n]
  float* wv    = cur + 6851072;       //    50,000
  float* VA    = nxt;                 // 6,400,000 [atom_v|non_v]

  const int nUI = U_N + V_N, nUA = U_N + A_N;
  const size_t CSR_BASE = 35520000;

  // CSR sizing (in 4B words): per graph rp(NR)+pos(NR)+ci(nnz)+cv(nnz)
  auto nr_pad = [](int nrows) { return (size_t)((nrows + 1 + 15) & ~15); };
  size_t sz_ui = 2 * nr_pad(nUI) + 2 * (size_t)nnz_ui;
  size_t sz_ua = 2 * nr_pad(nUA) + 2 * (size_t)nnz_ua;
  size_t sz_p3 = 2 * nr_pad(V_N) + 2 * (size_t)nnz_g4 +
                 2 * nr_pad(A_N) + 2 * (size_t)nnz_g2;
  size_t sz_max = sz_ui > sz_ua ? sz_ui : sz_ua;
  if (sz_p3 > sz_max) sz_max = sz_p3;
  bool use_csr = ws_size >= (CSR_BASE + sz_max + 64) * 4;

  auto build_csr = [&](const int* rows, const int* cols, const float* vals,
                       int nnz, int nrows, int* rp, int* pos, int* ci, float* cv) {
    hipMemsetAsync(pos, 0, (size_t)nrows * 4, stream);
    k_count<<<2048, 256, 0, stream>>>(rows, nnz, pos);
    k_scan<<<1, 1024, 0, stream>>>(pos, nrows, rp);
    k_fill<<<2048, 256, 0, stream>>>(rows, cols, vals, nnz, pos, ci, cv);
  };

  if (use_csr) {
    int* ib = (int*)(ws + CSR_BASE);
    // ---- UI propagation ----
    {
      size_t NR = nr_pad(nUI);
      int* rp = ib; int* pos = ib + NR; int* ci = ib + 2 * NR;
      float* cv = (float*)(ci + nnz_ui);
      build_csr(ui_rows, ui_cols, ui_vals, nnz_ui, nUI, rp, pos, ci, cv);
      k_concat2<<<2048, 256, 0, stream>>>(emb_user, U_N, emb_video, V_N, cur, accUI);
      float* p0 = cur; float* p1 = nxt;
      for (int l = 0; l < 3; ++l) {
        k_spmm_csr<<<2048, 256, 0, stream>>>(rp, ci, cv, nUI, p0, 0, p1, 64, 0, accUI);
        float* tmp = p0; p0 = p1; p1 = tmp;
      }
    }
    // ---- UA propagation ----
    {
      size_t NR = nr_pad(nUA);
      int* rp = ib; int* pos = ib + NR; int* ci = ib + 2 * NR;
      float* cv = (float*)(ci + nnz_ua);
      build_csr(ua_rows, ua_cols, ua_vals, nnz_ua, nUA, rp, pos, ci, cv);
      k_concat2<<<2048, 256, 0, stream>>>(emb_user, U_N, emb_vlogger, A_N, cur, accUA);
      float* p0 = cur; float* p1 = nxt;
      for (int l = 0; l < 3; ++l) {
        k_spmm_csr<<<2048, 256, 0, stream>>>(rp, ci, cv, nUA, p0, 0, p1, 64, 0, accUA);
        float* tmp = p0; p0 = p1; p1 = tmp;
      }
    }
    // ---- scales ----
    k_scale<<<2048, 256, 0, stream>>>(accUA, nUA * 16);
    k_scale_ui<<<2048, 256, 0, stream>>>(accUI, VA);
    // ---- g4 + g2 CSRs (packed) ----
    size_t NR4 = nr_pad(V_N), NR2 = nr_pad(A_N);
    int* rp4 = ib; int* pos4 = ib + NR4; int* ci4 = ib + 2 * NR4;
    float* cv4 = (float*)(ci4 + nnz_g4);
    int* ib2 = (int*)(cv4 + nnz_g4);
    int* rp2 = ib2; int* pos2 = ib2 + NR2; int* ci2 = ib2 + 2 * NR2;
    float* cv2 = (float*)(ci2 + nnz_g2);
    build_csr(g4_rows, g4_cols, g4_vals, nnz_g4, V_N, rp4, pos4, ci4, cv4);
    build_csr(g2_rows, g2_cols, g2_vals, nnz_g2, A_N, rp2, pos2, ci2, cv2);
    // ---- atom_a = l2norm(spmm(g2, atom_v)) ----
    k_spmm_csr<<<2048, 256, 0, stream>>>(rp2, ci2, cv2, A_N, accUI, U_N, atomA, 64, 0, nullptr);
    k_l2norm<<<1280, 256, 0, stream>>>(atomA, A_N, 64, 0);
    // ---- non_v = l2norm(spmm(g4, non_u)) into VA[:,64:] ----
    k_spmm_csr<<<2048, 256, 0, stream>>>(rp4, ci4, cv4, V_N, accUA, 0, VA, 128, 64, nullptr);
    k_l2norm<<<12500, 256, 0, stream>>>(VA, V_N, 128, 64);
  } else {
    // -------- fallback: atomic SpMM path (round-2 behavior) --------
    k_concat2<<<2048, 256, 0, stream>>>(emb_user, U_N, emb_video, V_N, cur, accUI);
    {
      float* p0 = cur; float* p1 = nxt;
      for (int l = 0; l < 3; ++l) {
        hipMemsetAsync(p1, 0, (size_t)nUI * 64 * 4, stream);
        k_spmm<<<8192, 256, 0, stream>>>(ui_rows, ui_cols, ui_vals, nnz_ui, p0, 0, p1, 64, 0);
        k_add<<<2048, 256, 0, stream>>>(accUI, p1, nUI * 16);
        float* tmp = p0; p0 = p1; p1 = tmp;
      }
    }
    k_concat2<<<2048, 256, 0, stream>>>(emb_user, U_N, emb_vlogger, A_N, cur, accUA);
    {
      float* p0 = cur; float* p1 = nxt;
      for (int l = 0; l < 3; ++l) {
        hipMemsetAsync(p1, 0, (size_t)nUA * 64 * 4, stream);
        k_spmm<<<8192, 256, 0, stream>>>(ua_rows, ua_cols, ua_vals, nnz_ua, p0, 0, p1, 64, 0);
        k_add<<<2048, 256, 0, stream>>>(accUA, p1, nUA * 16);
        float* tmp = p0; p0 = p1; p1 = tmp;
      }
    }
    k_scale<<<2048, 256, 0, stream>>>(accUA, nUA * 16);
    hipMemsetAsync(VA, 0, (size_t)V_N * 128 * 4, stream);
    k_scale_ui<<<2048, 256, 0, stream>>>(accUI, VA);
    hipMemsetAsync(atomA, 0, (size_t)A_N * 64 * 4, stream);
    k_spmm<<<2048, 256, 0, stream>>>(g2_rows, g2_cols, g2_vals, nnz_g2, accUI, U_N, atomA, 64, 0);
    k_l2norm<<<1280, 256, 0, stream>>>(atomA, A_N, 64, 0);
    k_spmm<<<8192, 256, 0, stream>>>(g4_rows, g4_cols, g4_vals, nnz_g4, accUA, 0, VA, 128, 64);
    k_l2norm<<<12500, 256, 0, stream>>>(VA, V_N, 128, 64);
  }

  // ---- gathers ----
  k_gather_u<<<1024, 64, 0, stream>>>(users, accUI, accUA, Ucat);
  k_gather_vb<<<12500, 256, 0, stream>>>(vlist, atomA, accUA, VB);
  // ---- w ----
  k_w<<<12500, 256, 0, stream>>>(VA, VB, q, wv);
  // ---- rating: 64x64 tiles, 4x4 register block ----
  dim3 gridR((V_N + 63) / 64, 1024 / 64);
  k_rating<<<gridR, 256, 0, stream>>>(Ucat, VA, VB, wv, (float*)d_out);
}

// Round 4
// 2282.848 us; speedup vs baseline: 2.1958x; 1.4027x over previous
//
#include <hip/hip_runtime.h>
#include <hip/hip_bf16.h>

#define U_N 100000
#define V_N 50000
#define A_N 5000

typedef float4 f4;
typedef unsigned int u32;
typedef __attribute__((ext_vector_type(8))) short bf16x8;
typedef __attribute__((ext_vector_type(4))) float f32x4;

__device__ inline float bflo(u32 p) { return __uint_as_float(p << 16); }
__device__ inline float bfhi(u32 p) { return __uint_as_float(p & 0xffff0000u); }
__device__ inline u32 f2bf(float f) {
  u32 u = __float_as_uint(f);
  return (u + 0x7fffu + ((u >> 16) & 1u)) >> 16;   // RTNE
}
__device__ inline u32 pack2(float lo, float hi) {
  return f2bf(lo) | (f2bf(hi) << 16);
}
__device__ inline bf16x8 ld8(const u32* p) {
  uint4 u = *(const uint4*)p;
  return __builtin_bit_cast(bf16x8, u);
}

// acc(fp32) = curH(bf16) = concat(a[na,64], b[nb,64])
__global__ void k_concat2b(const float* __restrict__ a, int na,
                           const float* __restrict__ b, int nb,
                           u32* __restrict__ curH, float* __restrict__ acc) {
  int total4 = (na + nb) * 16;
  for (int i = blockIdx.x * blockDim.x + threadIdx.x; i < total4;
       i += gridDim.x * blockDim.x) {
    int fi = i * 4;
    f4 v = (fi < na * 64) ? *(const f4*)(a + fi)
                          : *(const f4*)(b + (fi - na * 64));
    *(f4*)(acc + fi) = v;
    uint2 h; h.x = pack2(v.x, v.y); h.y = pack2(v.z, v.w);
    *(uint2*)(curH + (fi >> 1)) = h;
  }
}

// ---------------- CSR build ----------------
__global__ void k_count(const int* __restrict__ rows, int nnz, int* __restrict__ cnt) {
  for (int i = blockIdx.x * blockDim.x + threadIdx.x; i < nnz;
       i += gridDim.x * blockDim.x)
    atomicAdd(&cnt[rows[i]], 1);
}

__global__ void k_scan(int* __restrict__ cnt_pos, int n, int* __restrict__ rp) {
  __shared__ int part[1024];
  int t = threadIdx.x;
  int chunk = (n + 1023) >> 10;
  int b = t * chunk;
  int e = min(b + chunk, n);
  int s = 0;
  for (int i = b; i < e; ++i) s += cnt_pos[i];
  part[t] = s;
  __syncthreads();
  for (int off = 1; off < 1024; off <<= 1) {
    int v = (t >= off) ? part[t - off] : 0;
    __syncthreads();
    part[t] += v;
    __syncthreads();
  }
  int run = (t == 0) ? 0 : part[t - 1];
  for (int i = b; i < e; ++i) {
    int c = cnt_pos[i];
    rp[i] = run;
    cnt_pos[i] = run;
    run += c;
  }
  if (t == 1023) rp[n] = part[1023];
}

__global__ void k_fill(const int* __restrict__ rows, const int* __restrict__ cols,
                       const float* __restrict__ vals, int nnz,
                       int* __restrict__ pos, int* __restrict__ ci,
                       float* __restrict__ cv) {
  for (int i = blockIdx.x * blockDim.x + threadIdx.x; i < nnz;
       i += gridDim.x * blockDim.x) {
    int slot = atomicAdd(&pos[rows[i]], 1);
    ci[slot] = cols[i];
    cv[slot] = vals[i];
  }
}

// ---------------- bf16 gather SpMM: wave per row, 8 edges/iter ----------------
// inH: bf16 table, instrU uints per row. outH: bf16, ostrU stride, ocolU col offset.
// acc: optional fp32 +=. l2n: L2-normalize the row before writing.
__global__ void k_spmm_b(const int* __restrict__ rp, const int* __restrict__ ci,
                         const float* __restrict__ cv, int nrows,
                         const u32* __restrict__ inH, int instrU,
                         u32* __restrict__ outH, int ostrU, int ocolU,
                         float* __restrict__ acc, int l2n) {
  int lane = threadIdx.x & 63;
  int w = (blockIdx.x * blockDim.x + threadIdx.x) >> 6;
  int nw = (gridDim.x * blockDim.x) >> 6;
  int eg = lane >> 3;          // edge group 0..7
  int du = (lane & 7) * 4;     // uint offset in row (8 bf16 dims)
  for (int r = w; r < nrows; r += nw) {
    int e0 = rp[r], e1 = rp[r + 1];
    float s[8] = {0.f, 0.f, 0.f, 0.f, 0.f, 0.f, 0.f, 0.f};
    int e = e0 + eg;
    for (; e + 8 < e1; e += 16) {
      int c0 = ci[e];     float v0 = cv[e];
      int c1 = ci[e + 8]; float v1 = cv[e + 8];
      uint4 x0 = *(const uint4*)(inH + (size_t)c0 * instrU + du);
      uint4 x1 = *(const uint4*)(inH + (size_t)c1 * instrU + du);
      s[0] = fmaf(v0, bflo(x0.x), s[0]); s[1] = fmaf(v0, bfhi(x0.x), s[1]);
      s[2] = fmaf(v0, bflo(x0.y), s[2]); s[3] = fmaf(v0, bfhi(x0.y), s[3]);
      s[4] = fmaf(v0, bflo(x0.z), s[4]); s[5] = fmaf(v0, bfhi(x0.z), s[5]);
      s[6] = fmaf(v0, bflo(x0.w), s[6]); s[7] = fmaf(v0, bfhi(x0.w), s[7]);
      s[0] = fmaf(v1, bflo(x1.x), s[0]); s[1] = fmaf(v1, bfhi(x1.x), s[1]);
      s[2] = fmaf(v1, bflo(x1.y), s[2]); s[3] = fmaf(v1, bfhi(x1.y), s[3]);
      s[4] = fmaf(v1, bflo(x1.z), s[4]); s[5] = fmaf(v1, bfhi(x1.z), s[5]);
      s[6] = fmaf(v1, bflo(x1.w), s[6]); s[7] = fmaf(v1, bfhi(x1.w), s[7]);
    }
    if (e < e1) {
      int c0 = ci[e]; float v0 = cv[e];
      uint4 x0 = *(const uint4*)(inH + (size_t)c0 * instrU + du);
      s[0] = fmaf(v0, bflo(x0.x), s[0]); s[1] = fmaf(v0, bfhi(x0.x), s[1]);
      s[2] = fmaf(v0, bflo(x0.y), s[2]); s[3] = fmaf(v0, bfhi(x0.y), s[3]);
      s[4] = fmaf(v0, bflo(x0.z), s[4]); s[5] = fmaf(v0, bfhi(x0.z), s[5]);
      s[6] = fmaf(v0, bflo(x0.w), s[6]); s[7] = fmaf(v0, bfhi(x0.w), s[7]);
    }
    #pragma unroll
    for (int j = 0; j < 8; ++j) {
      s[j] += __shfl_xor(s[j], 8);
      s[j] += __shfl_xor(s[j], 16);
      s[j] += __shfl_xor(s[j], 32);
    }
    if (l2n) {
      float ss = 0.f;
      #pragma unroll
      for (int j = 0; j < 8; ++j) ss = fmaf(s[j], s[j], ss);
      ss += __shfl_xor(ss, 1);
      ss += __shfl_xor(ss, 2);
      ss += __shfl_xor(ss, 4);
      float inv = 1.0f / fmaxf(sqrtf(ss), 1e-12f);
      #pragma unroll
      for (int j = 0; j < 8; ++j) s[j] *= inv;
    }
    if (eg == 0) {
      uint4 o;
      o.x = pack2(s[0], s[1]); o.y = pack2(s[2], s[3]);
      o.z = pack2(s[4], s[5]); o.w = pack2(s[6], s[7]);
      *(uint4*)(outH + (size_t)r * ostrU + ocolU + du) = o;
      if (acc) {
        float* ap = acc + (size_t)r * 64 + (lane & 7) * 8;
        f4 a0 = *(f4*)ap, a1 = *(f4*)(ap + 4);
        a0.x += s[0]; a0.y += s[1]; a0.z += s[2]; a0.w += s[3];
        a1.x += s[4]; a1.y += s[5]; a1.z += s[6]; a1.w += s[7];
        *(f4*)ap = a0; *(f4*)(ap + 4) = a1;
      }
    }
  }
}

// accUA *= 0.25 in place; user rows also emitted bf16 to UAuH
__global__ void k_scale_ua(float* __restrict__ acc, u32* __restrict__ UAuH) {
  int total4 = (U_N + A_N) * 16;
  for (int i = blockIdx.x * blockDim.x + threadIdx.x; i < total4;
       i += gridDim.x * blockDim.x) {
    int fi = i * 4;
    f4 v = *(f4*)(acc + fi);
    v.x *= 0.25f; v.y *= 0.25f; v.z *= 0.25f; v.w *= 0.25f;
    *(f4*)(acc + fi) = v;
    if (fi < U_N * 64) {
      uint2 h; h.x = pack2(v.x, v.y); h.y = pack2(v.z, v.w);
      *(uint2*)(UAuH + (fi >> 1)) = h;
    }
  }
}

// accUI *= 0.25 in place; video rows emitted bf16 to VAH[:, :64] (stride 64 uints)
__global__ void k_scale_ui(float* __restrict__ acc, u32* __restrict__ VAH) {
  int total4 = (U_N + V_N) * 16;
  for (int i = blockIdx.x * blockDim.x + threadIdx.x; i < total4;
       i += gridDim.x * blockDim.x) {
    int fi = i * 4;
    f4 v = *(f4*)(acc + fi);
    v.x *= 0.25f; v.y *= 0.25f; v.z *= 0.25f; v.w *= 0.25f;
    *(f4*)(acc + fi) = v;
    if (fi >= U_N * 64) {
      int rem = fi - U_N * 64;
      int row = rem >> 6, col = rem & 63;
      uint2 h; h.x = pack2(v.x, v.y); h.y = pack2(v.z, v.w);
      *(uint2*)(VAH + (size_t)row * 64 + (col >> 1)) = h;
    }
  }
}

// UcatH[b] = bf16([atom_u[users[b]] | non_u[users[b]]]); 32 threads/block
__global__ void k_gather_u(const int* __restrict__ users,
                           const float* __restrict__ accUI,
                           const float* __restrict__ accUA,
                           u32* __restrict__ UcatH) {
  int b = blockIdx.x;
  int t = threadIdx.x;           // 0..31
  int u = users[b];
  UcatH[b * 64 + t] = pack2(accUI[(size_t)u * 64 + 2 * t], accUI[(size_t)u * 64 + 2 * t + 1]);
  UcatH[b * 64 + 32 + t] = pack2(accUA[(size_t)u * 64 + 2 * t], accUA[(size_t)u * 64 + 2 * t + 1]);
}

// VBH[v] = [atomAH[vl[v]] (bf16 copy) | bf16(non_a[vl[v]])]; 128 threads = 4 videos
__global__ void k_gather_vb(const int* __restrict__ vlist,
                            const u32* __restrict__ atomAH,
                            const float* __restrict__ accUA,
                            u32* __restrict__ VBH) {
  int v = blockIdx.x * 4 + (threadIdx.x >> 5);
  int t = threadIdx.x & 31;
  int a = vlist[v];
  VBH[(size_t)v * 64 + t] = atomAH[(size_t)a * 32 + t];
  VBH[(size_t)v * 64 + 32 + t] =
      pack2(accUA[(size_t)(U_N + a) * 64 + 2 * t], accUA[(size_t)(U_N + a) * 64 + 2 * t + 1]);
}

// w[v] = sigmoid( dot( ((atom_v+non_v)/2) @ q , (vl_a+vl_n)/2 ) ), bf16 tables
__global__ void k_w(const u32* __restrict__ VAH, const u32* __restrict__ VBH,
                    const float* __restrict__ q, float* __restrict__ wv) {
  __shared__ float qs[64 * 64];
  for (int i = threadIdx.x; i < 4096; i += blockDim.x) qs[i] = q[i];
  __syncthreads();
  int lane = threadIdx.x & 63;
  int v = blockIdx.x * 4 + (threadIdx.x >> 6);
  if (v >= V_N) return;
  int half = lane & 1;
  u32 pa0 = VAH[(size_t)v * 64 + (lane >> 1)];
  u32 pa1 = VAH[(size_t)v * 64 + 32 + (lane >> 1)];
  u32 pb0 = VBH[(size_t)v * 64 + (lane >> 1)];
  u32 pb1 = VBH[(size_t)v * 64 + 32 + (lane >> 1)];
  float vid = 0.5f * ((half ? bfhi(pa0) : bflo(pa0)) + (half ? bfhi(pa1) : bflo(pa1)));
  float vlog = 0.5f * ((half ? bfhi(pb0) : bflo(pb0)) + (half ? bfhi(pb1) : bflo(pb1)));
  float s = 0.0f;
  for (int d = 0; d < 64; ++d)
    s = fmaf(__shfl(vid, d, 64), qs[d * 64 + lane], s);
  float t = s * vlog;
  #pragma unroll
  for (int off = 32; off; off >>= 1) t += __shfl_xor(t, off, 64);
  if (lane == 0) wv[v] = 1.0f / (1.0f + __expf(-t));
}

// MFMA rating: block = 4 waves; wave = 64u x 64v; grid (ceil(V/64), 1024/256).
// out[u,v] = w[v]*sig(U·VA) + (1-w[v])*sig(U·VB)
__global__ __launch_bounds__(256) void k_rating_mfma(
    const u32* __restrict__ UcatH, const u32* __restrict__ VAH,
    const u32* __restrict__ VBH, const float* __restrict__ wv,
    float* __restrict__ out) {
  int lane = threadIdx.x & 63;
  int wave = threadIdx.x >> 6;
  int n0 = blockIdx.x * 64;
  int m0 = blockIdx.y * 256 + wave * 64;
  int rr = lane & 15, g = lane >> 4;
  f32x4 accA[4][4], accB[4][4];
  #pragma unroll
  for (int i = 0; i < 4; ++i)
    #pragma unroll
    for (int j = 0; j < 4; ++j) {
      accA[i][j] = (f32x4){0.f, 0.f, 0.f, 0.f};
      accB[i][j] = (f32x4){0.f, 0.f, 0.f, 0.f};
    }
  #pragma unroll
  for (int ks = 0; ks < 4; ++ks) {
    int ko = ks * 16 + g * 4;
    bf16x8 a[4], bA[4], bB[4];
    #pragma unroll
    for (int i = 0; i < 4; ++i)
      a[i] = ld8(UcatH + (size_t)(m0 + i * 16 + rr) * 64 + ko);
    #pragma unroll
    for (int j = 0; j < 4; ++j) {
      int nr = n0 + j * 16 + rr;
      if (nr >= V_N) nr = V_N - 1;
      bA[j] = ld8(VAH + (size_t)nr * 64 + ko);
      bB[j] = ld8(VBH + (size_t)nr * 64 + ko);
    }
    #pragma unroll
    for (int i = 0; i < 4; ++i)
      #pragma unroll
      for (int j = 0; j < 4; ++j) {
        accA[i][j] = __builtin_amdgcn_mfma_f32_16x16x32_bf16(a[i], bA[j], accA[i][j], 0, 0, 0);
        accB[i][j] = __builtin_amdgcn_mfma_f32_16x16x32_bf16(a[i], bB[j], accB[i][j], 0, 0, 0);
      }
  }
  // C/D: col = lane&15, row = g*4 + reg
  #pragma unroll
  for (int j = 0; j < 4; ++j) {
    int v = n0 + j * 16 + rr;
    if (v >= V_N) continue;
    float wvv = wv[v];
    #pragma unroll
    for (int i = 0; i < 4; ++i) {
      #pragma unroll
      for (int reg = 0; reg < 4; ++reg) {
        int u = m0 + i * 16 + g * 4 + reg;
        float sa = 1.0f / (1.0f + __expf(-accA[i][j][reg]));
        float sb = 1.0f / (1.0f + __expf(-accB[i][j][reg]));
        out[(size_t)u * V_N + v] = wvv * sa + (1.0f - wvv) * sb;
      }
    }
  }
}

extern "C" void kernel_launch(void* const* d_in, const int* in_sizes, int n_in,
                              void* d_out, int out_size, void* d_ws, size_t ws_size,
                              hipStream_t stream) {
  const float* emb_user    = (const float*)d_in[0];
  const float* emb_video   = (const float*)d_in[1];
  const float* emb_vlogger = (const float*)d_in[2];
  const float* q           = (const float*)d_in[3];
  const int*   ui_rows = (const int*)d_in[4];
  const int*   ui_cols = (const int*)d_in[5];
  const float* ui_vals = (const float*)d_in[6];
  const int*   ua_rows = (const int*)d_in[7];
  const int*   ua_cols = (const int*)d_in[8];
  const float* ua_vals = (const float*)d_in[9];
  const int*   g2_rows = (const int*)d_in[10];
  const int*   g2_cols = (const int*)d_in[11];
  const float* g2_vals = (const float*)d_in[12];
  const int*   g4_rows = (const int*)d_in[13];
  const int*   g4_cols = (const int*)d_in[14];
  const float* g4_vals = (const float*)d_in[15];
  const int*   vlist   = (const int*)d_in[16];
  const int*   users   = (const int*)d_in[17];
  int nnz_ui = in_sizes[4], nnz_ua = in_sizes[7];
  int nnz_g2 = in_sizes[10], nnz_g4 = in_sizes[13];

  float* ws = (float*)d_ws;
  float* accUI = ws;                       // 9,600,000 f
  float* accUA = ws + 9600000;             // 6,720,000 f
  u32*   curH  = (u32*)(ws + 16320000);    // 4,800,000 w (150000 x 32)
  u32*   nxtH  = (u32*)(ws + 21120000);    // 4,800,000 w
  u32*   VAH   = (u32*)(ws + 25920000);    // 3,200,000 w (50000 x 64)
  u32*   VBH   = (u32*)(ws + 29120000);    // 3,200,000 w
  u32*   UAuH  = (u32*)(ws + 32320000);    // 3,200,000 w (100000 x 32)
  u32*   UcatH = (u32*)(ws + 35520000);    //    65,536 w (1024 x 64)
  u32*   atomAH= (u32*)(ws + 35585536);    //   160,000 w (5000 x 32)
  float* wv    = ws + 35745536;            //    50,000 f
  int*   ib    = (int*)(ws + 35800000);    // CSR area (max ~8.31M words)

  const int nUI = U_N + V_N, nUA = U_N + A_N;
  auto nr_pad = [](int nrows) { return (size_t)((nrows + 1 + 15) & ~15); };

  auto build_csr = [&](const int* rows, const int* cols, const float* vals,
                       int nnz, int nrows, int* rp, int* pos, int* ci, float* cv) {
    hipMemsetAsync(pos, 0, (size_t)nrows * 4, stream);
    k_count<<<2048, 256, 0, stream>>>(rows, nnz, pos);
    k_scan<<<1, 1024, 0, stream>>>(pos, nrows, rp);
    k_fill<<<2048, 256, 0, stream>>>(rows, cols, vals, nnz, pos, ci, cv);
  };

  // ---- UI propagation ----
  {
    size_t NR = nr_pad(nUI);
    int* rp = ib; int* pos = ib + NR; int* ci = ib + 2 * NR;
    float* cv = (float*)(ci + nnz_ui);
    build_csr(ui_rows, ui_cols, ui_vals, nnz_ui, nUI, rp, pos, ci, cv);
    k_concat2b<<<2048, 256, 0, stream>>>(emb_user, U_N, emb_video, V_N, curH, accUI);
    u32* p0 = curH; u32* p1 = nxtH;
    for (int l = 0; l < 3; ++l) {
      k_spmm_b<<<2048, 256, 0, stream>>>(rp, ci, cv, nUI, p0, 32, p1, 32, 0, accUI, 0);
      u32* tmp = p0; p0 = p1; p1 = tmp;
    }
  }
  // ---- UA propagation ----
  {
    size_t NR = nr_pad(nUA);
    int* rp = ib; int* pos = ib + NR; int* ci = ib + 2 * NR;
    float* cv = (float*)(ci + nnz_ua);
    build_csr(ua_rows, ua_cols, ua_vals, nnz_ua, nUA, rp, pos, ci, cv);
    k_concat2b<<<2048, 256, 0, stream>>>(emb_user, U_N, emb_vlogger, A_N, curH, accUA);
    u32* p0 = curH; u32* p1 = nxtH;
    for (int l = 0; l < 3; ++l) {
      k_spmm_b<<<2048, 256, 0, stream>>>(rp, ci, cv, nUA, p0, 32, p1, 32, 0, accUA, 0);
      u32* tmp = p0; p0 = p1; p1 = tmp;
    }
  }
  // ---- scale to means + bf16 tables ----
  k_scale_ua<<<2048, 256, 0, stream>>>(accUA, UAuH);
  k_scale_ui<<<2048, 256, 0, stream>>>(accUI, VAH);
  // ---- g4 + g2 CSRs (packed) ----
  size_t NR4 = nr_pad(V_N), NR2 = nr_pad(A_N);
  int* rp4 = ib; int* pos4 = ib + NR4; int* ci4 = ib + 2 * NR4;
  float* cv4 = (float*)(ci4 + nnz_g4);
  int* ib2 = (int*)(cv4 + nnz_g4);
  int* rp2 = ib2; int* pos2 = ib2 + NR2; int* ci2 = ib2 + 2 * NR2;
  float* cv2 = (float*)(ci2 + nnz_g2);
  build_csr(g4_rows, g4_cols, g4_vals, nnz_g4, V_N, rp4, pos4, ci4, cv4);
  build_csr(g2_rows, g2_cols, g2_vals, nnz_g2, A_N, rp2, pos2, ci2, cv2);
  // ---- atomAH = l2norm(spmm(g2, atom_v)), input = VAH[:, :64-bf16] ----
  k_spmm_b<<<2048, 256, 0, stream>>>(rp2, ci2, cv2, A_N, VAH, 64, atomAH, 32, 0, nullptr, 1);
  // ---- non_v = l2norm(spmm(g4, non_u)) into VAH[:, 64:] ----
  k_spmm_b<<<2048, 256, 0, stream>>>(rp4, ci4, cv4, V_N, UAuH, 32, VAH, 64, 32, nullptr, 1);
  // ---- gathers ----
  k_gather_u<<<1024, 32, 0, stream>>>(users, accUI, accUA, UcatH);
  k_gather_vb<<<12500, 128, 0, stream>>>(vlist, atomAH, accUA, VBH);
  // ---- w ----
  k_w<<<12500, 256, 0, stream>>>(VAH, VBH, q, wv);
  // ---- rating (MFMA) ----
  dim3 gridR((V_N + 63) / 64, 1024 / 256);
  k_rating_mfma<<<gridR, 256, 0, stream>>>(UcatH, VAH, VBH, wv, (float*)d_out);
}

// Round 5
// 1678.698 us; speedup vs baseline: 2.9860x; 1.3599x over previous
//
#include <hip/hip_runtime.h>
#include <hip/hip_bf16.h>

#define U_N 100000
#define V_N 50000
#define A_N 5000

typedef float4 f4;
typedef unsigned int u32;
typedef __attribute__((ext_vector_type(8))) short bf16x8;
typedef __attribute__((ext_vector_type(4))) float f32x4;

__device__ inline float bflo(u32 p) { return __uint_as_float(p << 16); }
__device__ inline float bfhi(u32 p) { return __uint_as_float(p & 0xffff0000u); }
__device__ inline u32 f2bf(float f) {
  u32 u = __float_as_uint(f);
  return (u + 0x7fffu + ((u >> 16) & 1u)) >> 16;   // RTNE
}
__device__ inline u32 pack2(float lo, float hi) {
  return f2bf(lo) | (f2bf(hi) << 16);
}
__device__ inline bf16x8 ld8(const u32* p) {
  uint4 u = *(const uint4*)p;
  return __builtin_bit_cast(bf16x8, u);
}

// acc(fp32) = curH(bf16) = concat(a[na,64], b[nb,64])
__global__ void k_concat2b(const float* __restrict__ a, int na,
                           const float* __restrict__ b, int nb,
                           u32* __restrict__ curH, float* __restrict__ acc) {
  int total4 = (na + nb) * 16;
  for (int i = blockIdx.x * blockDim.x + threadIdx.x; i < total4;
       i += gridDim.x * blockDim.x) {
    int fi = i * 4;
    f4 v = (fi < na * 64) ? *(const f4*)(a + fi)
                          : *(const f4*)(b + (fi - na * 64));
    *(f4*)(acc + fi) = v;
    uint2 h; h.x = pack2(v.x, v.y); h.y = pack2(v.z, v.w);
    *(uint2*)(curH + (fi >> 1)) = h;
  }
}

// ---------------- CSR build ----------------
__global__ void k_count(const int* __restrict__ rows, int nnz, int* __restrict__ cnt) {
  for (int i = blockIdx.x * blockDim.x + threadIdx.x; i < nnz;
       i += gridDim.x * blockDim.x)
    atomicAdd(&cnt[rows[i]], 1);
}

// ---- hierarchical exclusive scan over cnt[0..n) -> rp[0..n], pos[i]=rp[i] ----
// 1) per-1024-chunk sums
__global__ void k_bsum(const int* __restrict__ cnt, int n, int* __restrict__ bsum) {
  __shared__ int red[1024];
  int t = threadIdx.x;
  int i = blockIdx.x * 1024 + t;
  red[t] = (i < n) ? cnt[i] : 0;
  __syncthreads();
  for (int off = 512; off; off >>= 1) {
    if (t < off) red[t] += red[t + off];
    __syncthreads();
  }
  if (t == 0) bsum[blockIdx.x] = red[0];
}

// 2) serial exclusive scan of chunk sums (nb <= ~150)
__global__ void k_bscan(int* __restrict__ bsum, int nb) {
  if (threadIdx.x == 0) {
    int run = 0;
    for (int i = 0; i < nb; ++i) {
      int c = bsum[i];
      bsum[i] = run;
      run += c;
    }
  }
}

// 3) per-chunk Hillis-Steele inclusive scan -> exclusive + chunk offset
__global__ void k_bapply(const int* __restrict__ cnt, int n,
                         const int* __restrict__ bsum,
                         int* __restrict__ rp, int* __restrict__ pos) {
  __shared__ int sc[1024];
  int t = threadIdx.x;
  int i = blockIdx.x * 1024 + t;
  int c = (i < n) ? cnt[i] : 0;
  sc[t] = c;
  __syncthreads();
  #pragma unroll
  for (int off = 1; off < 1024; off <<= 1) {
    int v = (t >= off) ? sc[t - off] : 0;
    __syncthreads();
    sc[t] += v;
    __syncthreads();
  }
  int val = bsum[blockIdx.x] + sc[t] - c;   // exclusive
  if (i < n) {
    rp[i] = val;
    pos[i] = val;
    if (i == n - 1) rp[n] = val + c;
  }
}

__global__ void k_fill(const int* __restrict__ rows, const int* __restrict__ cols,
                       const float* __restrict__ vals, int nnz,
                       int* __restrict__ pos, int* __restrict__ ci,
                       float* __restrict__ cv) {
  for (int i = blockIdx.x * blockDim.x + threadIdx.x; i < nnz;
       i += gridDim.x * blockDim.x) {
    int slot = atomicAdd(&pos[rows[i]], 1);
    ci[slot] = cols[i];
    cv[slot] = vals[i];
  }
}

// ---------------- bf16 gather SpMM: wave per row, 8 edges/iter ----------------
__global__ void k_spmm_b(const int* __restrict__ rp, const int* __restrict__ ci,
                         const float* __restrict__ cv, int nrows,
                         const u32* __restrict__ inH, int instrU,
                         u32* __restrict__ outH, int ostrU, int ocolU,
                         float* __restrict__ acc, int l2n) {
  int lane = threadIdx.x & 63;
  int w = (blockIdx.x * blockDim.x + threadIdx.x) >> 6;
  int nw = (gridDim.x * blockDim.x) >> 6;
  int eg = lane >> 3;          // edge group 0..7
  int du = (lane & 7) * 4;     // uint offset in row (8 bf16 dims)
  for (int r = w; r < nrows; r += nw) {
    int e0 = rp[r], e1 = rp[r + 1];
    float s[8] = {0.f, 0.f, 0.f, 0.f, 0.f, 0.f, 0.f, 0.f};
    int e = e0 + eg;
    for (; e + 8 < e1; e += 16) {
      int c0 = ci[e];     float v0 = cv[e];
      int c1 = ci[e + 8]; float v1 = cv[e + 8];
      uint4 x0 = *(const uint4*)(inH + (size_t)c0 * instrU + du);
      uint4 x1 = *(const uint4*)(inH + (size_t)c1 * instrU + du);
      s[0] = fmaf(v0, bflo(x0.x), s[0]); s[1] = fmaf(v0, bfhi(x0.x), s[1]);
      s[2] = fmaf(v0, bflo(x0.y), s[2]); s[3] = fmaf(v0, bfhi(x0.y), s[3]);
      s[4] = fmaf(v0, bflo(x0.z), s[4]); s[5] = fmaf(v0, bfhi(x0.z), s[5]);
      s[6] = fmaf(v0, bflo(x0.w), s[6]); s[7] = fmaf(v0, bfhi(x0.w), s[7]);
      s[0] = fmaf(v1, bflo(x1.x), s[0]); s[1] = fmaf(v1, bfhi(x1.x), s[1]);
      s[2] = fmaf(v1, bflo(x1.y), s[2]); s[3] = fmaf(v1, bfhi(x1.y), s[3]);
      s[4] = fmaf(v1, bflo(x1.z), s[4]); s[5] = fmaf(v1, bfhi(x1.z), s[5]);
      s[6] = fmaf(v1, bflo(x1.w), s[6]); s[7] = fmaf(v1, bfhi(x1.w), s[7]);
    }
    if (e < e1) {
      int c0 = ci[e]; float v0 = cv[e];
      uint4 x0 = *(const uint4*)(inH + (size_t)c0 * instrU + du);
      s[0] = fmaf(v0, bflo(x0.x), s[0]); s[1] = fmaf(v0, bfhi(x0.x), s[1]);
      s[2] = fmaf(v0, bflo(x0.y), s[2]); s[3] = fmaf(v0, bfhi(x0.y), s[3]);
      s[4] = fmaf(v0, bflo(x0.z), s[4]); s[5] = fmaf(v0, bfhi(x0.z), s[5]);
      s[6] = fmaf(v0, bflo(x0.w), s[6]); s[7] = fmaf(v0, bfhi(x0.w), s[7]);
    }
    #pragma unroll
    for (int j = 0; j < 8; ++j) {
      s[j] += __shfl_xor(s[j], 8);
      s[j] += __shfl_xor(s[j], 16);
      s[j] += __shfl_xor(s[j], 32);
    }
    if (l2n) {
      float ss = 0.f;
      #pragma unroll
      for (int j = 0; j < 8; ++j) ss = fmaf(s[j], s[j], ss);
      ss += __shfl_xor(ss, 1);
      ss += __shfl_xor(ss, 2);
      ss += __shfl_xor(ss, 4);
      float inv = 1.0f / fmaxf(sqrtf(ss), 1e-12f);
      #pragma unroll
      for (int j = 0; j < 8; ++j) s[j] *= inv;
    }
    if (eg == 0) {
      uint4 o;
      o.x = pack2(s[0], s[1]); o.y = pack2(s[2], s[3]);
      o.z = pack2(s[4], s[5]); o.w = pack2(s[6], s[7]);
      *(uint4*)(outH + (size_t)r * ostrU + ocolU + du) = o;
      if (acc) {
        float* ap = acc + (size_t)r * 64 + (lane & 7) * 8;
        f4 a0 = *(f4*)ap, a1 = *(f4*)(ap + 4);
        a0.x += s[0]; a0.y += s[1]; a0.z += s[2]; a0.w += s[3];
        a1.x += s[4]; a1.y += s[5]; a1.z += s[6]; a1.w += s[7];
        *(f4*)ap = a0; *(f4*)(ap + 4) = a1;
      }
    }
  }
}

// accUA *= 0.25 in place; user rows also emitted bf16 to UAuH
__global__ void k_scale_ua(float* __restrict__ acc, u32* __restrict__ UAuH) {
  int total4 = (U_N + A_N) * 16;
  for (int i = blockIdx.x * blockDim.x + threadIdx.x; i < total4;
       i += gridDim.x * blockDim.x) {
    int fi = i * 4;
    f4 v = *(f4*)(acc + fi);
    v.x *= 0.25f; v.y *= 0.25f; v.z *= 0.25f; v.w *= 0.25f;
    *(f4*)(acc + fi) = v;
    if (fi < U_N * 64) {
      uint2 h; h.x = pack2(v.x, v.y); h.y = pack2(v.z, v.w);
      *(uint2*)(UAuH + (fi >> 1)) = h;
    }
  }
}

// accUI *= 0.25 in place; video rows emitted bf16 to VAH[:, :64] (stride 64 uints)
__global__ void k_scale_ui(float* __restrict__ acc, u32* __restrict__ VAH) {
  int total4 = (U_N + V_N) * 16;
  for (int i = blockIdx.x * blockDim.x + threadIdx.x; i < total4;
       i += gridDim.x * blockDim.x) {
    int fi = i * 4;
    f4 v = *(f4*)(acc + fi);
    v.x *= 0.25f; v.y *= 0.25f; v.z *= 0.25f; v.w *= 0.25f;
    *(f4*)(acc + fi) = v;
    if (fi >= U_N * 64) {
      int rem = fi - U_N * 64;
      int row = rem >> 6, col = rem & 63;
      uint2 h; h.x = pack2(v.x, v.y); h.y = pack2(v.z, v.w);
      *(uint2*)(VAH + (size_t)row * 64 + (col >> 1)) = h;
    }
  }
}

// UcatH[b] = bf16([atom_u[users[b]] | non_u[users[b]]]); 32 threads/block
__global__ void k_gather_u(const int* __restrict__ users,
                           const float* __restrict__ accUI,
                           const float* __restrict__ accUA,
                           u32* __restrict__ UcatH) {
  int b = blockIdx.x;
  int t = threadIdx.x;           // 0..31
  int u = users[b];
  UcatH[b * 64 + t] = pack2(accUI[(size_t)u * 64 + 2 * t], accUI[(size_t)u * 64 + 2 * t + 1]);
  UcatH[b * 64 + 32 + t] = pack2(accUA[(size_t)u * 64 + 2 * t], accUA[(size_t)u * 64 + 2 * t + 1]);
}

// VBH[v] = [atomAH[vl[v]] (bf16 copy) | bf16(non_a[vl[v]])]; 128 threads = 4 videos
__global__ void k_gather_vb(const int* __restrict__ vlist,
                            const u32* __restrict__ atomAH,
                            const float* __restrict__ accUA,
                            u32* __restrict__ VBH) {
  int v = blockIdx.x * 4 + (threadIdx.x >> 5);
  int t = threadIdx.x & 31;
  int a = vlist[v];
  VBH[(size_t)v * 64 + t] = atomAH[(size_t)a * 32 + t];
  VBH[(size_t)v * 64 + 32 + t] =
      pack2(accUA[(size_t)(U_N + a) * 64 + 2 * t], accUA[(size_t)(U_N + a) * 64 + 2 * t + 1]);
}

// w[v] = sigmoid( dot( ((atom_v+non_v)/2) @ q , (vl_a+vl_n)/2 ) ), bf16 tables
__global__ void k_w(const u32* __restrict__ VAH, const u32* __restrict__ VBH,
                    const float* __restrict__ q, float* __restrict__ wv) {
  __shared__ float qs[64 * 64];
  for (int i = threadIdx.x; i < 4096; i += blockDim.x) qs[i] = q[i];
  __syncthreads();
  int lane = threadIdx.x & 63;
  int v = blockIdx.x * 4 + (threadIdx.x >> 6);
  if (v >= V_N) return;
  int half = lane & 1;
  u32 pa0 = VAH[(size_t)v * 64 + (lane >> 1)];
  u32 pa1 = VAH[(size_t)v * 64 + 32 + (lane >> 1)];
  u32 pb0 = VBH[(size_t)v * 64 + (lane >> 1)];
  u32 pb1 = VBH[(size_t)v * 64 + 32 + (lane >> 1)];
  float vid = 0.5f * ((half ? bfhi(pa0) : bflo(pa0)) + (half ? bfhi(pa1) : bflo(pa1)));
  float vlog = 0.5f * ((half ? bfhi(pb0) : bflo(pb0)) + (half ? bfhi(pb1) : bflo(pb1)));
  float s = 0.0f;
  for (int d = 0; d < 64; ++d)
    s = fmaf(__shfl(vid, d, 64), qs[d * 64 + lane], s);
  float t = s * vlog;
  #pragma unroll
  for (int off = 32; off; off >>= 1) t += __shfl_xor(t, off, 64);
  if (lane == 0) wv[v] = 1.0f / (1.0f + __expf(-t));
}

// MFMA rating: block = 4 waves; wave = 64u x 64v; grid (ceil(V/64), 1024/256).
__global__ __launch_bounds__(256) void k_rating_mfma(
    const u32* __restrict__ UcatH, const u32* __restrict__ VAH,
    const u32* __restrict__ VBH, const float* __restrict__ wv,
    float* __restrict__ out) {
  int lane = threadIdx.x & 63;
  int wave = threadIdx.x >> 6;
  int n0 = blockIdx.x * 64;
  int m0 = blockIdx.y * 256 + wave * 64;
  int rr = lane & 15, g = lane >> 4;
  f32x4 accA[4][4], accB[4][4];
  #pragma unroll
  for (int i = 0; i < 4; ++i)
    #pragma unroll
    for (int j = 0; j < 4; ++j) {
      accA[i][j] = (f32x4){0.f, 0.f, 0.f, 0.f};
      accB[i][j] = (f32x4){0.f, 0.f, 0.f, 0.f};
    }
  #pragma unroll
  for (int ks = 0; ks < 4; ++ks) {
    int ko = ks * 16 + g * 4;
    bf16x8 a[4], bA[4], bB[4];
    #pragma unroll
    for (int i = 0; i < 4; ++i)
      a[i] = ld8(UcatH + (size_t)(m0 + i * 16 + rr) * 64 + ko);
    #pragma unroll
    for (int j = 0; j < 4; ++j) {
      int nr = n0 + j * 16 + rr;
      if (nr >= V_N) nr = V_N - 1;
      bA[j] = ld8(VAH + (size_t)nr * 64 + ko);
      bB[j] = ld8(VBH + (size_t)nr * 64 + ko);
    }
    #pragma unroll
    for (int i = 0; i < 4; ++i)
      #pragma unroll
      for (int j = 0; j < 4; ++j) {
        accA[i][j] = __builtin_amdgcn_mfma_f32_16x16x32_bf16(a[i], bA[j], accA[i][j], 0, 0, 0);
        accB[i][j] = __builtin_amdgcn_mfma_f32_16x16x32_bf16(a[i], bB[j], accB[i][j], 0, 0, 0);
      }
  }
  // C/D: col = lane&15, row = g*4 + reg
  #pragma unroll
  for (int j = 0; j < 4; ++j) {
    int v = n0 + j * 16 + rr;
    if (v >= V_N) continue;
    float wvv = wv[v];
    #pragma unroll
    for (int i = 0; i < 4; ++i) {
      #pragma unroll
      for (int reg = 0; reg < 4; ++reg) {
        int u = m0 + i * 16 + g * 4 + reg;
        float sa = 1.0f / (1.0f + __expf(-accA[i][j][reg]));
        float sb = 1.0f / (1.0f + __expf(-accB[i][j][reg]));
        out[(size_t)u * V_N + v] = wvv * sa + (1.0f - wvv) * sb;
      }
    }
  }
}

extern "C" void kernel_launch(void* const* d_in, const int* in_sizes, int n_in,
                              void* d_out, int out_size, void* d_ws, size_t ws_size,
                              hipStream_t stream) {
  const float* emb_user    = (const float*)d_in[0];
  const float* emb_video   = (const float*)d_in[1];
  const float* emb_vlogger = (const float*)d_in[2];
  const float* q           = (const float*)d_in[3];
  const int*   ui_rows = (const int*)d_in[4];
  const int*   ui_cols = (const int*)d_in[5];
  const float* ui_vals = (const float*)d_in[6];
  const int*   ua_rows = (const int*)d_in[7];
  const int*   ua_cols = (const int*)d_in[8];
  const float* ua_vals = (const float*)d_in[9];
  const int*   g2_rows = (const int*)d_in[10];
  const int*   g2_cols = (const int*)d_in[11];
  const float* g2_vals = (const float*)d_in[12];
  const int*   g4_rows = (const int*)d_in[13];
  const int*   g4_cols = (const int*)d_in[14];
  const float* g4_vals = (const float*)d_in[15];
  const int*   vlist   = (const int*)d_in[16];
  const int*   users   = (const int*)d_in[17];
  int nnz_ui = in_sizes[4], nnz_ua = in_sizes[7];
  int nnz_g2 = in_sizes[10], nnz_g4 = in_sizes[13];

  float* ws = (float*)d_ws;
  float* accUI = ws;                       // 9,600,000 f
  float* accUA = ws + 9600000;             // 6,720,000 f
  u32*   curH  = (u32*)(ws + 16320000);    // 4,800,000 w (150000 x 32)
  u32*   nxtH  = (u32*)(ws + 21120000);    // 4,800,000 w
  u32*   VAH   = (u32*)(ws + 25920000);    // 3,200,000 w (50000 x 64)
  u32*   VBH   = (u32*)(ws + 29120000);    // 3,200,000 w
  u32*   UAuH  = (u32*)(ws + 32320000);    // 3,200,000 w (100000 x 32)
  u32*   UcatH = (u32*)(ws + 35520000);    //    65,536 w (1024 x 64)
  u32*   atomAH= (u32*)(ws + 35585536);    //   160,000 w (5000 x 32)
  float* wv    = ws + 35745536;            //    50,000 f
  int*   bsum  = (int*)(ws + 35795536);    //       256 w (scan partials)
  int*   ib    = (int*)(ws + 35800000);    // CSR area (max ~8.31M words)

  const int nUI = U_N + V_N, nUA = U_N + A_N;
  auto nr_pad = [](int nrows) { return (size_t)((nrows + 1 + 15) & ~15); };

  auto build_csr = [&](const int* rows, const int* cols, const float* vals,
                       int nnz, int nrows, int* rp, int* pos, int* ci, float* cv) {
    hipMemsetAsync(pos, 0, (size_t)nrows * 4, stream);
    k_count<<<2048, 256, 0, stream>>>(rows, nnz, pos);
    int nb = (nrows + 1023) / 1024;
    k_bsum<<<nb, 1024, 0, stream>>>(pos, nrows, bsum);
    k_bscan<<<1, 64, 0, stream>>>(bsum, nb);
    k_bapply<<<nb, 1024, 0, stream>>>(pos, nrows, bsum, rp, pos);
    k_fill<<<2048, 256, 0, stream>>>(rows, cols, vals, nnz, pos, ci, cv);
  };

  // ---- UI propagation ----
  {
    size_t NR = nr_pad(nUI);
    int* rp = ib; int* pos = ib + NR; int* ci = ib + 2 * NR;
    float* cv = (float*)(ci + nnz_ui);
    build_csr(ui_rows, ui_cols, ui_vals, nnz_ui, nUI, rp, pos, ci, cv);
    k_concat2b<<<2048, 256, 0, stream>>>(emb_user, U_N, emb_video, V_N, curH, accUI);
    u32* p0 = curH; u32* p1 = nxtH;
    for (int l = 0; l < 3; ++l) {
      k_spmm_b<<<2048, 256, 0, stream>>>(rp, ci, cv, nUI, p0, 32, p1, 32, 0, accUI, 0);
      u32* tmp = p0; p0 = p1; p1 = tmp;
    }
  }
  // ---- UA propagation ----
  {
    size_t NR = nr_pad(nUA);
    int* rp = ib; int* pos = ib + NR; int* ci = ib + 2 * NR;
    float* cv = (float*)(ci + nnz_ua);
    build_csr(ua_rows, ua_cols, ua_vals, nnz_ua, nUA, rp, pos, ci, cv);
    k_concat2b<<<2048, 256, 0, stream>>>(emb_user, U_N, emb_vlogger, A_N, curH, accUA);
    u32* p0 = curH; u32* p1 = nxtH;
    for (int l = 0; l < 3; ++l) {
      k_spmm_b<<<2048, 256, 0, stream>>>(rp, ci, cv, nUA, p0, 32, p1, 32, 0, accUA, 0);
      u32* tmp = p0; p0 = p1; p1 = tmp;
    }
  }
  // ---- scale to means + bf16 tables ----
  k_scale_ua<<<2048, 256, 0, stream>>>(accUA, UAuH);
  k_scale_ui<<<2048, 256, 0, stream>>>(accUI, VAH);
  // ---- g4 + g2 CSRs (packed) ----
  size_t NR4 = nr_pad(V_N), NR2 = nr_pad(A_N);
  int* rp4 = ib; int* pos4 = ib + NR4; int* ci4 = ib + 2 * NR4;
  float* cv4 = (float*)(ci4 + nnz_g4);
  int* ib2 = (int*)(cv4 + nnz_g4);
  int* rp2 = ib2; int* pos2 = ib2 + NR2; int* ci2 = ib2 + 2 * NR2;
  float* cv2 = (float*)(ci2 + nnz_g2);
  build_csr(g4_rows, g4_cols, g4_vals, nnz_g4, V_N, rp4, pos4, ci4, cv4);
  build_csr(g2_rows, g2_cols, g2_vals, nnz_g2, A_N, rp2, pos2, ci2, cv2);
  // ---- atomAH = l2norm(spmm(g2, atom_v)), input = VAH[:, :64-bf16 half] ----
  k_spmm_b<<<2048, 256, 0, stream>>>(rp2, ci2, cv2, A_N, VAH, 64, atomAH, 32, 0, nullptr, 1);
  // ---- non_v = l2norm(spmm(g4, non_u)) into VAH[:, 64:] ----
  k_spmm_b<<<2048, 256, 0, stream>>>(rp4, ci4, cv4, V_N, UAuH, 32, VAH, 64, 32, nullptr, 1);
  // ---- gathers ----
  k_gather_u<<<1024, 32, 0, stream>>>(users, accUI, accUA, UcatH);
  k_gather_vb<<<12500, 128, 0, stream>>>(vlist, atomAH, accUA, VBH);
  // ---- w ----
  k_w<<<12500, 256, 0, stream>>>(VAH, VBH, q, wv);
  // ---- rating (MFMA) ----
  dim3 gridR((V_N + 63) / 64, 1024 / 256);
  k_rating_mfma<<<gridR, 256, 0, stream>>>(UcatH, VAH, VBH, wv, (float*)d_out);
}